// Round 4
// baseline (475.029 us; speedup 1.0000x reference)
//
#include <hip/hip_runtime.h>

#define H 1024
#define W 1024
#define HW (H * W)

// Bit-exact emulation of the numpy fp32 reference:
//   direct 9-tap correlation, row-major tap order, sequential fp32 adds.
// fmaf with +-2/+-4 coefficients is BIT-IDENTICAL to mul+add here: products
// by powers of two are exact, so fma rounds the same exact sum.
// det = p1 - p2 must NOT be contracted (p1, p2 inexact) -> contract(off).
__device__ __forceinline__ float score_ref(
    float a00, float a01, float a02,
    float a10, float a11, float a12,
    float a20, float a21, float a22)
{
#pragma clang fp contract(off)
    // KXX = [[1,-2,1],[2,-4,2],[1,-2,1]], row-major order
    float gxx = fmaf(-2.0f, a01, a00);
    gxx = gxx + a02;
    gxx = fmaf(2.0f, a10, gxx);
    gxx = fmaf(-4.0f, a11, gxx);
    gxx = fmaf(2.0f, a12, gxx);
    gxx = gxx + a20;
    gxx = fmaf(-2.0f, a21, gxx);
    gxx = gxx + a22;
    // KXY = [[-1,0,1],[0,0,0],[1,0,-1]]
    float gxy = a02 - a00;      // == (-a00 + a02) bitwise
    gxy = gxy + a20;
    gxy = gxy - a22;
    // KYY = [[1,2,1],[-2,-4,-2],[1,2,1]]
    float gyy = fmaf(2.0f, a01, a00);
    gyy = gyy + a02;
    gyy = fmaf(-2.0f, a10, gyy);
    gyy = fmaf(-4.0f, a11, gyy);
    gyy = fmaf(-2.0f, a12, gyy);
    gyy = gyy + a20;
    gyy = fmaf(2.0f, a21, gyy);
    gyy = gyy + a22;

    float p1 = gxx * gyy;
    float p2 = gxy * gxy;
    float det = p1 - p2;
    float s = fabsf(det);
    return s > 1e-6f ? s : 1e-6f;
}

// ======================= main path (needs 192 MiB ws) =======================

// K1: compute all scores once, store to ws, reduce per-plane max.
// grid (H/32, planes), block 256; thread t owns cols 4t..4t+3, rolling 3-row
// window over 32 rows.
__global__ __launch_bounds__(256) void hess_score_max_kernel(
    const float* __restrict__ x, float* __restrict__ sc,
    unsigned int* __restrict__ pmax)
{
    const int plane = blockIdx.y;
    const int y0 = blockIdx.x * 32;
    const int t = threadIdx.x;
    const int c = t * 4;
    const float* px = x + (size_t)plane * HW;
    float* psc = sc + (size_t)plane * HW;

    float l0, l1, l2, r0, r1, r2;
    float4 m0, m1, m2;

    {   // row y0-1 (clamped)
        int rr = y0 - 1 < 0 ? 0 : y0 - 1;
        const float* p = px + (size_t)rr * W;
        m0 = *(const float4*)(p + c);
        l0 = p[c == 0 ? 0 : c - 1];
        r0 = p[c + 4 >= W ? W - 1 : c + 4];
    }
    {   // row y0
        const float* p = px + (size_t)y0 * W;
        m1 = *(const float4*)(p + c);
        l1 = p[c == 0 ? 0 : c - 1];
        r1 = p[c + 4 >= W ? W - 1 : c + 4];
    }

    float smax = 0.f;
    for (int y = y0; y < y0 + 32; ++y) {
        int rr = y + 1 >= H ? H - 1 : y + 1;
        const float* p = px + (size_t)rr * W;
        m2 = *(const float4*)(p + c);
        l2 = p[c == 0 ? 0 : c - 1];
        r2 = p[c + 4 >= W ? W - 1 : c + 4];

        float w0[6] = { l0, m0.x, m0.y, m0.z, m0.w, r0 };
        float w1[6] = { l1, m1.x, m1.y, m1.z, m1.w, r1 };
        float w2[6] = { l2, m2.x, m2.y, m2.z, m2.w, r2 };
        float s[4];
#pragma unroll
        for (int j = 0; j < 4; ++j) {
            s[j] = score_ref(w0[j], w0[j+1], w0[j+2],
                             w1[j], w1[j+1], w1[j+2],
                             w2[j], w2[j+1], w2[j+2]);
            smax = fmaxf(smax, s[j]);
        }
        *(float4*)(psc + (size_t)y * W + c) = make_float4(s[0], s[1], s[2], s[3]);
        m0 = m1; l0 = l1; r0 = r1;
        m1 = m2; l1 = l2; r1 = r2;
    }

#pragma unroll
    for (int off = 32; off > 0; off >>= 1)
        smax = fmaxf(smax, __shfl_down(smax, off));
    if ((t & 63) == 0)
        atomicMax(pmax + plane, __float_as_uint(smax));
}

// K2: NMS + normalize from the stored score field.
#define TW 128
#define TH 16
#define SW 132          // TW+2 used, padded to TW+4 (528 B row pitch, 16B-aligned)
#define SH 18           // TH+2
__global__ __launch_bounds__(256) void hess_nms_kernel(
    const float* __restrict__ sc, const unsigned int* __restrict__ pmax,
    float* __restrict__ out)
{
    __shared__ float ls[SH * SW];
    const int plane = blockIdx.z;
    const int x0 = blockIdx.x * TW;
    const int y0 = blockIdx.y * TH;
    const int t = threadIdx.x;
    const float* ps = sc + (size_t)plane * HW;

    // stage score tile + 1-halo; OOB -> 0 (identity for max; scores >= 1e-6)
    for (int i = t; i < SH * SW; i += 256) {
        int sy = i / SW, sx = i - sy * SW;
        int gy = y0 - 1 + sy, gx = x0 - 1 + sx;
        float v = 0.f;
        if (gy >= 0 && gy < H && gx >= 0 && gx < W)
            v = ps[(size_t)gy * W + gx];
        ls[i] = v;
    }
    __syncthreads();

    const float inv = 1.0f / __uint_as_float(pmax[plane]);
    const int cc = (t & 31) * 4;     // 0..124
    const int r0 = t >> 5;           // 0..7
    float* po = out + (size_t)plane * HW;

#pragma unroll
    for (int k = 0; k < 2; ++k) {
        const int r = r0 + k * 8;    // 0..15
        const float* b0 = &ls[(r + 0) * SW + cc];
        const float* b1 = &ls[(r + 1) * SW + cc];
        const float* b2 = &ls[(r + 2) * SW + cc];
        float4 o;
        float* ov = (float*)&o;
#pragma unroll
        for (int j = 0; j < 4; ++j) {
            float s = b1[j + 1];
            float m = fmaxf(fmaxf(fmaxf(b0[j], b0[j+1]), fmaxf(b0[j+2], b1[j])),
                            fmaxf(fmaxf(b1[j+1], b1[j+2]),
                                  fmaxf(fmaxf(b2[j], b2[j+1]), b2[j+2])));
            ov[j] = (s == m) ? s * inv : 0.f;
        }
        *(float4*)(po + (size_t)(y0 + r) * W + (x0 + cc)) = o;
    }
}

// ==================== fallback path (tiny ws): R3 kernels ====================

__global__ __launch_bounds__(256) void hess_max_fb(
    const float* __restrict__ x, unsigned int* __restrict__ pmax)
{
    const int plane = blockIdx.y;
    const int y0 = blockIdx.x * 32;
    const int t = threadIdx.x;
    const int c = t * 4;
    const float* px = x + (size_t)plane * HW;

    float l0, l1, l2, r0, r1, r2;
    float4 m0, m1, m2;
    {
        int rr = y0 - 1 < 0 ? 0 : y0 - 1;
        const float* p = px + (size_t)rr * W;
        m0 = *(const float4*)(p + c);
        l0 = p[c == 0 ? 0 : c - 1];
        r0 = p[c + 4 >= W ? W - 1 : c + 4];
    }
    {
        const float* p = px + (size_t)y0 * W;
        m1 = *(const float4*)(p + c);
        l1 = p[c == 0 ? 0 : c - 1];
        r1 = p[c + 4 >= W ? W - 1 : c + 4];
    }
    float smax = 0.f;
    for (int y = y0; y < y0 + 32; ++y) {
        int rr = y + 1 >= H ? H - 1 : y + 1;
        const float* p = px + (size_t)rr * W;
        m2 = *(const float4*)(p + c);
        l2 = p[c == 0 ? 0 : c - 1];
        r2 = p[c + 4 >= W ? W - 1 : c + 4];
        float w0[6] = { l0, m0.x, m0.y, m0.z, m0.w, r0 };
        float w1[6] = { l1, m1.x, m1.y, m1.z, m1.w, r1 };
        float w2[6] = { l2, m2.x, m2.y, m2.z, m2.w, r2 };
#pragma unroll
        for (int j = 0; j < 4; ++j)
            smax = fmaxf(smax, score_ref(w0[j], w0[j+1], w0[j+2],
                                         w1[j], w1[j+1], w1[j+2],
                                         w2[j], w2[j+1], w2[j+2]));
        m0 = m1; l0 = l1; r0 = r1;
        m1 = m2; l1 = l2; r1 = r2;
    }
#pragma unroll
    for (int off = 32; off > 0; off >>= 1)
        smax = fmaxf(smax, __shfl_down(smax, off));
    if ((t & 63) == 0)
        atomicMax(pmax + plane, __float_as_uint(smax));
}

#define FTW 64
#define FTH 16
#define FIW 68
#define FIH 20
#define FSW 66
#define FSH 18
__global__ __launch_bounds__(256) void hess_out_fb(
    const float* __restrict__ x, const unsigned int* __restrict__ pmax,
    float* __restrict__ out)
{
    __shared__ float lin[FIH * FIW];
    __shared__ float ls[FSH * FSW];
    const int plane = blockIdx.z;
    const int x0 = blockIdx.x * FTW;
    const int y0 = blockIdx.y * FTH;
    const int t = threadIdx.x;
    const float* px = x + (size_t)plane * HW;

    for (int i = t; i < FIH * FIW; i += 256) {
        int r = i / FIW, cc = i % FIW;
        int gy = y0 - 2 + r; gy = gy < 0 ? 0 : (gy >= H ? H - 1 : gy);
        int gx = x0 - 2 + cc; gx = gx < 0 ? 0 : (gx >= W ? W - 1 : gx);
        lin[i] = px[(size_t)gy * W + gx];
    }
    __syncthreads();
    for (int i = t; i < FSH * FSW; i += 256) {
        int sy = i / FSW, sx = i % FSW;
        int gy = y0 - 1 + sy, gx = x0 - 1 + sx;
        float v = 0.f;
        if (gy >= 0 && gy < H && gx >= 0 && gx < W) {
            const float* p0 = &lin[sy * FIW + sx];
            v = score_ref(p0[0], p0[1], p0[2],
                          p0[FIW], p0[FIW + 1], p0[FIW + 2],
                          p0[2 * FIW], p0[2 * FIW + 1], p0[2 * FIW + 2]);
        }
        ls[i] = v;
    }
    __syncthreads();
    const float inv = 1.0f / __uint_as_float(pmax[plane]);
    const int ox = t & 63;
    const int oyb = t >> 6;
#pragma unroll
    for (int k = 0; k < 4; ++k) {
        int oy = oyb * 4 + k;
        const float* p = &ls[oy * FSW + ox];
        float s = p[FSW + 1];
        float m = fmaxf(fmaxf(fmaxf(p[0], p[1]), fmaxf(p[2], p[FSW])),
                        fmaxf(fmaxf(p[FSW + 1], p[FSW + 2]),
                              fmaxf(fmaxf(p[2 * FSW], p[2 * FSW + 1]), p[2 * FSW + 2])));
        float v = (s == m) ? s * inv : 0.f;
        out[(size_t)plane * HW + (size_t)(y0 + oy) * W + (x0 + ox)] = v;
    }
}

extern "C" void kernel_launch(void* const* d_in, const int* in_sizes, int n_in,
                              void* d_out, int out_size, void* d_ws, size_t ws_size,
                              hipStream_t stream) {
    const float* x = (const float*)d_in[0];
    float* out = (float*)d_out;
    const int planes = in_sizes[0] / HW;   // 48

    const size_t sc_bytes = (size_t)planes * HW * sizeof(float);

    if (ws_size >= sc_bytes + planes * sizeof(unsigned int)) {
        float* sc = (float*)d_ws;
        unsigned int* pmax = (unsigned int*)((char*)d_ws + sc_bytes);
        hipMemsetAsync(pmax, 0, planes * sizeof(unsigned int), stream);

        dim3 g1(H / 32, planes);
        hess_score_max_kernel<<<g1, 256, 0, stream>>>(x, sc, pmax);

        dim3 g2(W / TW, H / TH, planes);
        hess_nms_kernel<<<g2, 256, 0, stream>>>(sc, pmax, out);
    } else {
        unsigned int* pmax = (unsigned int*)d_ws;
        hipMemsetAsync(pmax, 0, planes * sizeof(unsigned int), stream);

        dim3 g1(H / 32, planes);
        hess_max_fb<<<g1, 256, 0, stream>>>(x, pmax);

        dim3 g2(W / FTW, H / FTH, planes);
        hess_out_fb<<<g2, 256, 0, stream>>>(x, pmax, out);
    }
}

// Round 5
// 422.765 us; speedup vs baseline: 1.1236x; 1.1236x over previous
//
#include <hip/hip_runtime.h>

#define H 1024
#define W 1024
#define HW (H * W)
#define STRIP 16

// Bit-exact emulation of the numpy fp32 reference (verified R3/R4, absmax 0):
// direct 9-tap correlation, row-major tap order, sequential fp32 adds.
// fmaf by +-2/+-4 is bit-identical to mul+add (power-of-2 products exact).
// det = p1 - p2 must NOT be contracted -> contract(off).
__device__ __forceinline__ float score_ref(
    float a00, float a01, float a02,
    float a10, float a11, float a12,
    float a20, float a21, float a22)
{
#pragma clang fp contract(off)
    float gxx = fmaf(-2.0f, a01, a00);
    gxx = gxx + a02;
    gxx = fmaf(2.0f, a10, gxx);
    gxx = fmaf(-4.0f, a11, gxx);
    gxx = fmaf(2.0f, a12, gxx);
    gxx = gxx + a20;
    gxx = fmaf(-2.0f, a21, gxx);
    gxx = gxx + a22;
    float gxy = a02 - a00;
    gxy = gxy + a20;
    gxy = gxy - a22;
    float gyy = fmaf(2.0f, a01, a00);
    gyy = gyy + a02;
    gyy = fmaf(-2.0f, a10, gyy);
    gyy = fmaf(-4.0f, a11, gyy);
    gyy = fmaf(-2.0f, a12, gyy);
    gyy = gyy + a20;
    gyy = fmaf(2.0f, a21, gyy);
    gyy = gyy + a22;

    float p1 = gxx * gyy;
    float p2 = gxy * gxy;
    float det = p1 - p2;
    float s = fabsf(det);
    return s > 1e-6f ? s : 1e-6f;
}

// One row of 8 input columns (c-2 .. c+5) per thread, all aligned loads:
// float4 at c (16B-aligned), float2 at c-2 (8B), float2 at c+4 (8B).
// Horizontal edge-replicate fixups only affect threads 0 and 255.
struct Row8 { float a[8]; };

__device__ __forceinline__ Row8 load_row8(const float* __restrict__ prow, int c, int t)
{
    const float4 m = *(const float4*)(prow + c);
    int lc = c - 2; lc = lc < 0 ? 0 : lc;                 // only t==0
    const float2 L = *(const float2*)(prow + lc);
    int rc = c + 4; rc = rc > (W - 2) ? (W - 2) : rc;     // only t==255
    const float2 R = *(const float2*)(prow + rc);
    float l0 = L.x, l1 = L.y;
    if (t == 0) l1 = L.x;       // col -1 -> x[0]  (l0: col -2 -> x[0] already)
    float q0 = R.x, q1 = R.y;
    if (t == 255) q0 = R.y;     // col 1024 -> x[1023] (q1: col 1025 -> x[1023] already)
    Row8 r;
    r.a[0] = l0; r.a[1] = l1;
    r.a[2] = m.x; r.a[3] = m.y; r.a[4] = m.z; r.a[5] = m.w;
    r.a[6] = q0; r.a[7] = q1;
    return r;
}

// ---------------- K1: per-plane max (order-free math -> separable) ----------
__global__ __launch_bounds__(256) void hess_max_kernel(
    const float* __restrict__ x, unsigned int* __restrict__ pmax)
{
    const int plane = blockIdx.y;
    const int y0 = blockIdx.x * STRIP;
    const int t = threadIdx.x;
    const int c = t * 4;
    const float* px = x + (size_t)plane * HW;

    Row8 r0 = load_row8(px + (size_t)(y0 - 1 < 0 ? 0 : y0 - 1) * W, c, t);
    Row8 r1 = load_row8(px + (size_t)y0 * W, c, t);
    Row8 r2 = load_row8(px + (size_t)(y0 + 1 > H - 1 ? H - 1 : y0 + 1) * W, c, t);
    Row8 r3 = load_row8(px + (size_t)(y0 + 2 > H - 1 ? H - 1 : y0 + 2) * W, c, t);

    float smax = 1e-6f;
#pragma unroll
    for (int i = 0; i < STRIP; ++i) {
        const int sy = y0 + i;
        const int pf = sy + 3 > H - 1 ? H - 1 : sy + 3;
        Row8 r4 = load_row8(px + (size_t)pf * W, c, t);

        float P[6], Q[6], Rv[6];
#pragma unroll
        for (int k = 0; k < 6; ++k) {
            // vertical partials at col c-1+k (a-index k+1)
            P[k] = fmaf(2.0f, r1.a[k + 1], r0.a[k + 1]) + r2.a[k + 1];
            Q[k] = fmaf(-2.0f, r1.a[k + 1], r0.a[k + 1]) + r2.a[k + 1];
            Rv[k] = r0.a[k + 1] - r2.a[k + 1];
        }
#pragma unroll
        for (int j = 0; j < 4; ++j) {
            float gxx = fmaf(-2.0f, P[j + 1], P[j]) + P[j + 2];
            float gyy = fmaf(2.0f, Q[j + 1], Q[j]) + Q[j + 2];
            float gxy = Rv[j + 2] - Rv[j];
            float det = fmaf(gxx, gyy, -(gxy * gxy));
            smax = fmaxf(smax, fabsf(det));
        }
        r0 = r1; r1 = r2; r2 = r3; r3 = r4;
    }

#pragma unroll
    for (int off = 32; off > 0; off >>= 1)
        smax = fmaxf(smax, __shfl_down(smax, off));
    if ((t & 63) == 0)
        atomicMax(pmax + plane, __float_as_uint(smax));
}

// ---------------- K2: bit-exact scores + NMS + normalize --------------------
struct S6 { float s[6]; };   // scores at cols c-1 .. c+4

__device__ __forceinline__ S6 score_row_exact(const Row8& A, const Row8& B, const Row8& C)
{
    S6 o;
#pragma unroll
    for (int i = 0; i < 6; ++i)
        o.s[i] = score_ref(A.a[i], A.a[i + 1], A.a[i + 2],
                           B.a[i], B.a[i + 1], B.a[i + 2],
                           C.a[i], C.a[i + 1], C.a[i + 2]);
    return o;
}

__global__ __launch_bounds__(256) void hess_nms_kernel(
    const float* __restrict__ x, const unsigned int* __restrict__ pmax,
    float* __restrict__ out)
{
    const int plane = blockIdx.y;
    const int y0 = blockIdx.x * STRIP;
    const int t = threadIdx.x;
    const int c = t * 4;
    const float* px = x + (size_t)plane * HW;
    float* po = out + (size_t)plane * HW;
    const float inv = 1.0f / __uint_as_float(pmax[plane]);

    Row8 rm2 = load_row8(px + (size_t)(y0 - 2 < 0 ? 0 : y0 - 2) * W, c, t);
    Row8 r0  = load_row8(px + (size_t)(y0 - 1 < 0 ? 0 : y0 - 1) * W, c, t);
    Row8 r1  = load_row8(px + (size_t)y0 * W, c, t);
    Row8 r2  = load_row8(px + (size_t)(y0 + 1 > H - 1 ? H - 1 : y0 + 1) * W, c, t);
    Row8 r3  = load_row8(px + (size_t)(y0 + 2 > H - 1 ? H - 1 : y0 + 2) * W, c, t);

    S6 zero;
#pragma unroll
    for (int i = 0; i < 6; ++i) zero.s[i] = 0.0f;

    // score row y0-1 (OOB -> zeros, the identity for the 3x3 max)
    S6 sp = zero;
    if (y0 > 0) sp = score_row_exact(rm2, r0, r1);
    S6 sc_ = score_row_exact(r0, r1, r2);

#pragma unroll
    for (int i = 0; i < STRIP; ++i) {
        const int sy = y0 + i;
        const int pf = sy + 3 > H - 1 ? H - 1 : sy + 3;
        Row8 r4 = load_row8(px + (size_t)pf * W, c, t);

        S6 sn = zero;
        if (sy + 1 < H) sn = score_row_exact(r1, r2, r3);

        float4 o;
        float* ov = (float*)&o;
#pragma unroll
        for (int j = 0; j < 4; ++j) {
            float s = sc_.s[j + 1];
            float m = fmaxf(fmaxf(fmaxf(sp.s[j], sp.s[j + 1]), fmaxf(sp.s[j + 2], sc_.s[j])),
                            fmaxf(fmaxf(sc_.s[j + 1], sc_.s[j + 2]),
                                  fmaxf(fmaxf(sn.s[j], sn.s[j + 1]), sn.s[j + 2])));
            ov[j] = (s == m) ? s * inv : 0.0f;
        }
        *(float4*)(po + (size_t)sy * W + c) = o;

        r0 = r1; r1 = r2; r2 = r3; r3 = r4;
        sp = sc_; sc_ = sn;
    }
}

extern "C" void kernel_launch(void* const* d_in, const int* in_sizes, int n_in,
                              void* d_out, int out_size, void* d_ws, size_t ws_size,
                              hipStream_t stream) {
    const float* x = (const float*)d_in[0];
    float* out = (float*)d_out;
    unsigned int* pmax = (unsigned int*)d_ws;
    const int planes = in_sizes[0] / HW;   // 48

    hipMemsetAsync(pmax, 0, planes * sizeof(unsigned int), stream);

    dim3 grid(H / STRIP, planes);
    hess_max_kernel<<<grid, 256, 0, stream>>>(x, pmax);
    hess_nms_kernel<<<grid, 256, 0, stream>>>(x, pmax, out);
}